// Round 1
// baseline (9278.901 us; speedup 1.0000x reference)
//
#include <hip/hip_runtime.h>
#include <hip/hip_bf16.h>

// ---------------------------------------------------------------------------
// SpaceTimeTransformer (TimeSformer divided space-time attention) on MI355X.
// Round 1: correctness-first. bf16 MFMA GEMMs (128x128 tile, global_load_lds),
// fp32 vector attention, fp32 residual stream.
// B=4, F=8, N=196, S=1569, D=768, H=12, d=64, L=12, HID=3072.
// M = B*S = 6276, padded to Mp = 6400 (50 tiles of 128).
// ---------------------------------------------------------------------------

#define DEV __device__ __forceinline__

typedef __bf16 bf16x8 __attribute__((ext_vector_type(8)));
typedef float f32x4 __attribute__((ext_vector_type(4)));

static constexpr int D = 768;
static constexpr int S = 1569;   // 1 + 8*196
static constexpr int B = 4;
static constexpr int NH = 12;
static constexpr int NF = 8;
static constexpr int NP = 196;
static constexpr int M  = B * S;        // 6276
static constexpr int Mp = 6400;         // padded rows

DEV void gload16(const void* g, void* l) {
  __builtin_amdgcn_global_load_lds((const __attribute__((address_space(1))) void*)g,
                                   (__attribute__((address_space(3))) void*)l, 16, 0, 0);
}

DEV ushort f2bfu(float f) {
  __hip_bfloat16 h = __float2bfloat16(f);
  return *reinterpret_cast<ushort*>(&h);
}

// ---------------------------------------------------------------------------
// Generic GEMM: C[M x N] = A[M x K] @ B[N x K]^T + bias, epilogue variants.
// EPI 0: Cf = acc + bias                (fp32 out)
// EPI 1: Cf = acc + bias + res          (fp32 out)
// EPI 2: Cb = bf16(gelu(acc + bias))    (bf16 out)
// grid = (N/128, Mtiles). A rows must be readable up to Mtiles*128.
// ---------------------------------------------------------------------------
template<int EPI>
__global__ __launch_bounds__(256)
void gemm_bt(const __hip_bfloat16* __restrict__ A,
             const __hip_bfloat16* __restrict__ Bw,
             const float* __restrict__ bias,
             const float* __restrict__ res,
             float* __restrict__ Cf,
             __hip_bfloat16* __restrict__ Cb,
             int N, int K)
{
  __shared__ __hip_bfloat16 As[128 * 64];
  __shared__ __hip_bfloat16 Bs[128 * 64];
  const int tid  = threadIdx.x;
  const int lane = tid & 63;
  const int wave = tid >> 6;
  const int wm = wave >> 1, wn = wave & 1;
  const int bm = blockIdx.y * 128, bn = blockIdx.x * 128;

  const int srow = lane >> 3;          // row within 8-row chunk
  const int scol = (lane & 7) * 8;     // element col within 64

  const int lrow = lane & 15;
  const int lk   = (lane >> 4) * 8;

  f32x4 acc[4][4] = {};

  for (int k0 = 0; k0 < K; k0 += 64) {
    #pragma unroll
    for (int c = 0; c < 4; ++c) {
      const int r = wave * 32 + c * 8;
      gload16(A  + (size_t)(bm + r + srow) * K + k0 + scol, &As[r * 64]);
      gload16(Bw + (size_t)(bn + r + srow) * K + k0 + scol, &Bs[r * 64]);
    }
    __syncthreads();
    #pragma unroll
    for (int kk = 0; kk < 2; ++kk) {
      bf16x8 af[4], bfr[4];
      #pragma unroll
      for (int m = 0; m < 4; ++m)
        af[m] = *reinterpret_cast<const bf16x8*>(&As[(wm*64 + m*16 + lrow)*64 + kk*32 + lk]);
      #pragma unroll
      for (int n = 0; n < 4; ++n)
        bfr[n] = *reinterpret_cast<const bf16x8*>(&Bs[(wn*64 + n*16 + lrow)*64 + kk*32 + lk]);
      #pragma unroll
      for (int m = 0; m < 4; ++m)
        #pragma unroll
        for (int n = 0; n < 4; ++n)
          acc[m][n] = __builtin_amdgcn_mfma_f32_16x16x32_bf16(af[m], bfr[n], acc[m][n], 0, 0, 0);
    }
    __syncthreads();
  }

  const int crow0 = bm + wm*64 + (lane >> 4) * 4;
  const int ccol0 = bn + wn*64 + (lane & 15);
  #pragma unroll
  for (int m = 0; m < 4; ++m) {
    #pragma unroll
    for (int n = 0; n < 4; ++n) {
      #pragma unroll
      for (int i = 0; i < 4; ++i) {
        const int row = crow0 + m*16 + i;
        const int col = ccol0 + n*16;
        const size_t off = (size_t)row * N + col;
        float v = acc[m][n][i] + bias[col];
        if (EPI == 1) {
          Cf[off] = v + res[off];
        } else if (EPI == 2) {
          float g = 0.5f * v * (1.0f + erff(v * 0.70710678118654752f));
          Cb[off] = __float2bfloat16(g);
        } else {
          Cf[off] = v;
        }
      }
    }
  }
}

// ---------------------------------------------------------------------------
// LayerNorm over D=768, fp32 in -> bf16 out (GEMM A input). One block per row.
// ---------------------------------------------------------------------------
__global__ __launch_bounds__(256)
void ln_bf16_kernel(const float* __restrict__ in, const float* __restrict__ sc,
                    const float* __restrict__ bb, __hip_bfloat16* __restrict__ out)
{
  __shared__ float red[4];
  const int row = blockIdx.x, tid = threadIdx.x;
  const float* x = in + (size_t)row * D;
  float x0 = x[tid], x1 = x[tid + 256], x2 = x[tid + 512];
  float s = x0 + x1 + x2;
  for (int o = 32; o; o >>= 1) s += __shfl_down(s, o);
  if ((tid & 63) == 0) red[tid >> 6] = s;
  __syncthreads();
  const float mean = (red[0] + red[1] + red[2] + red[3]) * (1.f / 768.f);
  __syncthreads();
  const float d0 = x0 - mean, d1 = x1 - mean, d2 = x2 - mean;
  float v = d0*d0 + d1*d1 + d2*d2;
  for (int o = 32; o; o >>= 1) v += __shfl_down(v, o);
  if ((tid & 63) == 0) red[tid >> 6] = v;
  __syncthreads();
  const float var = (red[0] + red[1] + red[2] + red[3]) * (1.f / 768.f);
  const float r = rsqrtf(var + 1e-6f);
  __hip_bfloat16* orow = out + (size_t)row * D;
  orow[tid]       = __float2bfloat16(d0 * r * sc[tid]       + bb[tid]);
  orow[tid + 256] = __float2bfloat16(d1 * r * sc[tid + 256] + bb[tid + 256]);
  orow[tid + 512] = __float2bfloat16(d2 * r * sc[tid + 512] + bb[tid + 512]);
}

// Final LayerNorm of CLS rows only -> fp32 d_out (4 x 768).
__global__ __launch_bounds__(256)
void ln_final_kernel(const float* __restrict__ in, const float* __restrict__ sc,
                     const float* __restrict__ bb, float* __restrict__ out)
{
  __shared__ float red[4];
  const int b = blockIdx.x, tid = threadIdx.x;
  const float* x = in + (size_t)(b * S) * D;
  float x0 = x[tid], x1 = x[tid + 256], x2 = x[tid + 512];
  float s = x0 + x1 + x2;
  for (int o = 32; o; o >>= 1) s += __shfl_down(s, o);
  if ((tid & 63) == 0) red[tid >> 6] = s;
  __syncthreads();
  const float mean = (red[0] + red[1] + red[2] + red[3]) * (1.f / 768.f);
  __syncthreads();
  const float d0 = x0 - mean, d1 = x1 - mean, d2 = x2 - mean;
  float v = d0*d0 + d1*d1 + d2*d2;
  for (int o = 32; o; o >>= 1) v += __shfl_down(v, o);
  if ((tid & 63) == 0) red[tid >> 6] = v;
  __syncthreads();
  const float var = (red[0] + red[1] + red[2] + red[3]) * (1.f / 768.f);
  const float r = rsqrtf(var + 1e-6f);
  float* orow = out + (size_t)b * D;
  orow[tid]       = d0 * r * sc[tid]       + bb[tid];
  orow[tid + 256] = d1 * r * sc[tid + 256] + bb[tid + 256];
  orow[tid + 512] = d2 * r * sc[tid + 512] + bb[tid + 512];
}

// ---------------------------------------------------------------------------
// CLS attention: per (b,h), 1 query over all S=1569 keys. grid = 48.
// qkv layout: [b*S + s][3*D], q at +0, k at +768, v at +1536, head h at h*64.
// Output written as bf16 into attn-out buffer (row b*S, col h*64..).
// ---------------------------------------------------------------------------
__global__ __launch_bounds__(256)
void cls_attn_kernel(const float* __restrict__ qkv, __hip_bfloat16* __restrict__ out)
{
  __shared__ float qs[64];
  __shared__ float sims[S];
  __shared__ float opart[4][64];
  __shared__ float red[4];
  const int b = blockIdx.x / NH, h = blockIdx.x % NH;
  const int tid = threadIdx.x;
  const float* base = qkv + (size_t)b * S * 2304;
  if (tid < 64) qs[tid] = base[h * 64 + tid] * 0.125f;
  __syncthreads();
  float lmax = -1e30f;
  for (int j = tid; j < S; j += 256) {
    const float* kr = base + (size_t)j * 2304 + 768 + h * 64;
    float sacc = 0.f;
    #pragma unroll
    for (int c = 0; c < 16; ++c) {
      float4 kv = *(const float4*)(kr + c * 4);
      sacc += qs[c*4+0]*kv.x + qs[c*4+1]*kv.y + qs[c*4+2]*kv.z + qs[c*4+3]*kv.w;
    }
    sims[j] = sacc;
    lmax = fmaxf(lmax, sacc);
  }
  for (int o = 32; o; o >>= 1) lmax = fmaxf(lmax, __shfl_down(lmax, o));
  if ((tid & 63) == 0) red[tid >> 6] = lmax;
  __syncthreads();
  const float m = fmaxf(fmaxf(red[0], red[1]), fmaxf(red[2], red[3]));
  __syncthreads();
  float lsum = 0.f;
  for (int j = tid; j < S; j += 256) {
    float p = __expf(sims[j] - m);
    sims[j] = p;
    lsum += p;
  }
  for (int o = 32; o; o >>= 1) lsum += __shfl_down(lsum, o);
  if ((tid & 63) == 0) red[tid >> 6] = lsum;
  __syncthreads();
  const float l = red[0] + red[1] + red[2] + red[3];
  const int wave = tid >> 6, lane = tid & 63;
  float oa = 0.f;
  for (int j = wave; j < S; j += 4) {
    const float* vr = base + (size_t)j * 2304 + 1536 + h * 64;
    oa += sims[j] * vr[lane];
  }
  opart[wave][lane] = oa;
  __syncthreads();
  if (tid < 64) {
    float o = (opart[0][tid] + opart[1][tid] + opart[2][tid] + opart[3][tid]) / l;
    out[(size_t)(b * S) * D + h * 64 + tid] = __float2bfloat16(o);
  }
}

// ---------------------------------------------------------------------------
// Time attention: group = (b,h,n); 8 queries (frames) x 9 keys (CLS + 8).
// One wave per group, 4 groups per block. grid = 9408/4 = 2352.
// ---------------------------------------------------------------------------
__global__ __launch_bounds__(256)
void time_attn_kernel(const float* __restrict__ qkv, __hip_bfloat16* __restrict__ out)
{
  __shared__ float Ks[4][9][64];
  __shared__ float Vs[4][9][64];
  const int tid = threadIdx.x;
  const int grp = tid >> 6, lane = tid & 63;
  const int g = blockIdx.x * 4 + grp;
  const int n = g % NP;
  const int h = (g / NP) % NH;
  const int b = g / (NP * NH);
  const float* base = qkv + (size_t)b * S * 2304;
  #pragma unroll
  for (int j = 0; j < 9; ++j) {
    const int sj = (j == 0) ? 0 : (1 + (j - 1) * NP + n);
    const float* r = base + (size_t)sj * 2304 + h * 64;
    Ks[grp][j][lane] = r[768 + lane];
    Vs[grp][j][lane] = r[1536 + lane];
  }
  const int qi = lane >> 3, sub = lane & 7;
  const int sq = 1 + qi * NP + n;
  const float* qp = base + (size_t)sq * 2304 + h * 64 + sub * 8;
  float4 q0 = *(const float4*)qp;
  float4 q1 = *(const float4*)(qp + 4);
  float qf[8] = {q0.x, q0.y, q0.z, q0.w, q1.x, q1.y, q1.z, q1.w};
  #pragma unroll
  for (int t = 0; t < 8; ++t) qf[t] *= 0.125f;
  __syncthreads();
  float sim[9];
  #pragma unroll
  for (int j = 0; j < 9; ++j) {
    float p = 0.f;
    #pragma unroll
    for (int t = 0; t < 8; ++t) p += qf[t] * Ks[grp][j][sub * 8 + t];
    p += __shfl_xor(p, 1, 8);
    p += __shfl_xor(p, 2, 8);
    p += __shfl_xor(p, 4, 8);
    sim[j] = p;
  }
  float m = sim[0];
  #pragma unroll
  for (int j = 1; j < 9; ++j) m = fmaxf(m, sim[j]);
  float l = 0.f;
  #pragma unroll
  for (int j = 0; j < 9; ++j) { sim[j] = __expf(sim[j] - m); l += sim[j]; }
  const float inv = 1.f / l;
  float o[8] = {};
  #pragma unroll
  for (int j = 0; j < 9; ++j)
    #pragma unroll
    for (int t = 0; t < 8; ++t) o[t] += sim[j] * Vs[grp][j][sub * 8 + t];
  union { ushort us[8]; uint4 v; } pk;
  #pragma unroll
  for (int t = 0; t < 8; ++t) pk.us[t] = f2bfu(o[t] * inv);
  *(uint4*)(out + (size_t)(b * S + sq) * D + h * 64 + sub * 8) = pk.v;
}

// ---------------------------------------------------------------------------
// Space attention: group = (b,h,f); 196 queries x 197 keys (CLS + 196).
// One block (256 thr) per group; K/V staged bf16 in LDS; thread-per-query
// online softmax with deferred rescale (THR=8). grid = 384.
// ---------------------------------------------------------------------------
__global__ __launch_bounds__(256, 2)
void space_attn_kernel(const float* __restrict__ qkv, __hip_bfloat16* __restrict__ out)
{
  __shared__ __hip_bfloat16 Ks[197][64];
  __shared__ __hip_bfloat16 Vs[197][64];
  const int tid = threadIdx.x;
  const int f = blockIdx.x & 7;
  const int h = (blockIdx.x >> 3) % NH;
  const int b = blockIdx.x / (NH * NF);
  const float* base = qkv + (size_t)b * S * 2304;
  for (int idx = tid; idx < 197 * 8; idx += 256) {
    const int j = idx >> 3, c = (idx & 7) * 8;
    const int sj = (j == 0) ? 0 : (1 + f * NP + j - 1);
    const float* r = base + (size_t)sj * 2304 + h * 64 + c;
    float4 k0 = *(const float4*)(r + 768);
    float4 k1 = *(const float4*)(r + 772);
    float4 v0 = *(const float4*)(r + 1536);
    float4 v1 = *(const float4*)(r + 1540);
    __hip_bfloat16* kp = &Ks[j][c];
    kp[0] = __float2bfloat16(k0.x); kp[1] = __float2bfloat16(k0.y);
    kp[2] = __float2bfloat16(k0.z); kp[3] = __float2bfloat16(k0.w);
    kp[4] = __float2bfloat16(k1.x); kp[5] = __float2bfloat16(k1.y);
    kp[6] = __float2bfloat16(k1.z); kp[7] = __float2bfloat16(k1.w);
    __hip_bfloat16* vp = &Vs[j][c];
    vp[0] = __float2bfloat16(v0.x); vp[1] = __float2bfloat16(v0.y);
    vp[2] = __float2bfloat16(v0.z); vp[3] = __float2bfloat16(v0.w);
    vp[4] = __float2bfloat16(v1.x); vp[5] = __float2bfloat16(v1.y);
    vp[6] = __float2bfloat16(v1.z); vp[7] = __float2bfloat16(v1.w);
  }
  __syncthreads();
  const int n = tid;
  if (n < NP) {
    const int sq = 1 + f * NP + n;
    const float* qp = base + (size_t)sq * 2304 + h * 64;
    float qf[64];
    #pragma unroll
    for (int c = 0; c < 16; ++c) {
      float4 q = *(const float4*)(qp + c * 4);
      qf[c*4+0] = q.x * 0.125f; qf[c*4+1] = q.y * 0.125f;
      qf[c*4+2] = q.z * 0.125f; qf[c*4+3] = q.w * 0.125f;
    }
    float m = -1e30f, l = 0.f;
    float o[64] = {};
    for (int j = 0; j < 197; ++j) {
      const uint* kr = (const uint*)&Ks[j][0];
      float sacc = 0.f;
      #pragma unroll
      for (int c = 0; c < 32; ++c) {
        const uint u = kr[c];
        sacc += qf[2*c]   * __uint_as_float(u << 16);
        sacc += qf[2*c+1] * __uint_as_float(u & 0xffff0000u);
      }
      if (sacc > m + 8.f) {
        const float corr = __expf(m - sacc);
        l *= corr;
        #pragma unroll
        for (int dd = 0; dd < 64; ++dd) o[dd] *= corr;
        m = sacc;
      }
      const float p = __expf(sacc - m);
      l += p;
      const uint* vr = (const uint*)&Vs[j][0];
      #pragma unroll
      for (int c = 0; c < 32; ++c) {
        const uint u = vr[c];
        o[2*c]   += p * __uint_as_float(u << 16);
        o[2*c+1] += p * __uint_as_float(u & 0xffff0000u);
      }
    }
    const float inv = 1.f / l;
    __hip_bfloat16* orow = out + (size_t)(b * S + sq) * D + h * 64;
    #pragma unroll
    for (int c8 = 0; c8 < 8; ++c8) {
      union { ushort us[8]; uint4 v; } pk;
      #pragma unroll
      for (int t = 0; t < 8; ++t) pk.us[t] = f2bfu(o[c8 * 8 + t] * inv);
      *(uint4*)(orow + c8 * 8) = pk.v;
    }
  }
}

// ---------------------------------------------------------------------------
// Patch embedding im2col: x (4,8,3,224,224) -> A (6272, 768) bf16,
// col = c*256 + py*16 + px.
// ---------------------------------------------------------------------------
__global__ __launch_bounds__(256)
void im2col_kernel(const float* __restrict__ x, __hip_bfloat16* __restrict__ A)
{
  const int idx = blockIdx.x * 256 + threadIdx.x;   // < 6272*768
  const int col = idx % 768;
  const int row = idx / 768;
  const int px = col & 15, py = (col >> 4) & 15, c = col >> 8;
  const int pw = row % 14, ph = (row / 14) % 14, bf = row / 196;
  const float v = x[(((size_t)bf * 3 + c) * 224 + ph * 16 + py) * 224 + pw * 16 + px];
  A[idx] = __float2bfloat16(v);
}

// Assemble token stream: xt[b][s][d] = patch/cls + pos + temporal embeds.
__global__ __launch_bounds__(256)
void assemble_kernel(const float* __restrict__ xp, const float* __restrict__ cls,
                     const float* __restrict__ pos, const float* __restrict__ temb,
                     float* __restrict__ xt)
{
  const int idx = blockIdx.x * 256 + threadIdx.x;   // < 4*1569*768
  const int d = idx % D;
  const int s = (idx / D) % S;
  const int b = idx / (D * S);
  float v;
  if (s == 0) {
    v = cls[d] + pos[d];
  } else {
    const int j = s - 1, f = j / NP, nn = j % NP;
    v = xp[((size_t)(b * NF + f) * NP + nn) * D + d]
        + pos[(size_t)(1 + nn) * D + d] + temb[(size_t)f * D + d];
  }
  xt[((size_t)b * S + s) * D + d] = v;
}

// Convert one layer's 6 weight matrices fp32 -> bf16 into packed buffer.
// Layout: [time_qkv | time_proj | attn_qkv | attn_proj | fc1 | fc2]
__global__ __launch_bounds__(256)
void wconv6_kernel(const float* __restrict__ tq, const float* __restrict__ tp,
                   const float* __restrict__ aq, const float* __restrict__ ap,
                   const float* __restrict__ f1, const float* __restrict__ f2,
                   __hip_bfloat16* __restrict__ dst)
{
  const size_t i = ((size_t)blockIdx.x * 256 + threadIdx.x) * 4;  // < 9437184
  const float* src;
  size_t off = i;
  if      (i < 1769472u) { src = tq; }
  else if (i < 2359296u) { src = tp; off = i - 1769472u; }
  else if (i < 4128768u) { src = aq; off = i - 2359296u; }
  else if (i < 4718592u) { src = ap; off = i - 4128768u; }
  else if (i < 7077888u) { src = f1; off = i - 4718592u; }
  else                   { src = f2; off = i - 7077888u; }
  const float4 v = *(const float4*)(src + off);
  union { ushort us[4]; uint2 u; } pk;
  pk.us[0] = f2bfu(v.x); pk.us[1] = f2bfu(v.y);
  pk.us[2] = f2bfu(v.z); pk.us[3] = f2bfu(v.w);
  *(uint2*)(dst + i) = pk.u;
}

__global__ __launch_bounds__(256)
void wconv1_kernel(const float* __restrict__ src, __hip_bfloat16* __restrict__ dst)
{
  const size_t i = ((size_t)blockIdx.x * 256 + threadIdx.x) * 4;  // < 589824
  const float4 v = *(const float4*)(src + i);
  union { ushort us[4]; uint2 u; } pk;
  pk.us[0] = f2bfu(v.x); pk.us[1] = f2bfu(v.y);
  pk.us[2] = f2bfu(v.z); pk.us[3] = f2bfu(v.w);
  *(uint2*)(dst + i) = pk.u;
}

// ---------------------------------------------------------------------------
extern "C" void kernel_launch(void* const* d_in, const int* in_sizes, int n_in,
                              void* d_out, int out_size, void* d_ws, size_t ws_size,
                              hipStream_t stream) {
  (void)in_sizes; (void)n_in; (void)out_size; (void)ws_size;
  const float* x       = (const float*)d_in[0];
  const float* patch_w = (const float*)d_in[1];
  const float* patch_b = (const float*)d_in[2];
  const float* cls_t   = (const float*)d_in[3];
  const float* pos_e   = (const float*)d_in[4];
  const float* tem_e   = (const float*)d_in[5];
  const float* n1s = (const float*)d_in[6];
  const float* n1b = (const float*)d_in[7];
  const float* n2s = (const float*)d_in[8];
  const float* n2b = (const float*)d_in[9];
  const float* n3s = (const float*)d_in[10];
  const float* n3b = (const float*)d_in[11];
  const float* aqw = (const float*)d_in[12];
  const float* aqb = (const float*)d_in[13];
  const float* apw = (const float*)d_in[14];
  const float* apb = (const float*)d_in[15];
  const float* tqw = (const float*)d_in[16];
  const float* tqb = (const float*)d_in[17];
  const float* tpw = (const float*)d_in[18];
  const float* tpb = (const float*)d_in[19];
  const float* f1w = (const float*)d_in[20];
  const float* f1b = (const float*)d_in[21];
  const float* f2w = (const float*)d_in[22];
  const float* f2b = (const float*)d_in[23];
  const float* nfs = (const float*)d_in[24];
  const float* nfb = (const float*)d_in[25];
  float* outp = (float*)d_out;

  // workspace layout (bytes)
  char* ws = (char*)d_ws;
  float* xt  = (float*)(ws);                          // 6400*768 f32   = 19,660,800
  float* rs  = (float*)(ws + 19660800);               // 6400*768 f32   = 19,660,800
  float* qkv = (float*)(ws + 39321600);               // 6400*2304 f32  = 58,982,400
  __hip_bfloat16* abf = (__hip_bfloat16*)(ws + 98304000);   // 6400*3072 bf16 = 39,321,600
  __hip_bfloat16* wbf = (__hip_bfloat16*)(ws + 137625600);  // 9,437,184 bf16 = 18,874,368
  __hip_bfloat16* hdn = (__hip_bfloat16*)qkv;         // fc1 gelu out aliases qkv buf

  // weight segment offsets (elements)
  const size_t O_TQ = 0, O_TP = 1769472, O_AQ = 2359296, O_AP = 4128768,
               O_F1 = 4718592, O_F2 = 7077888;

  // ---- patch embedding ----
  im2col_kernel<<<18816, 256, 0, stream>>>(x, abf);
  wconv1_kernel<<<576, 256, 0, stream>>>(patch_w, wbf);
  gemm_bt<0><<<dim3(6, 49), 256, 0, stream>>>(abf, wbf, patch_b, nullptr, qkv, nullptr, 768, 768);
  assemble_kernel<<<18828, 256, 0, stream>>>(qkv, cls_t, pos_e, tem_e, xt);

  for (int i = 0; i < 12; ++i) {
    wconv6_kernel<<<9216, 256, 0, stream>>>(
        tqw + (size_t)i * 1769472, tpw + (size_t)i * 589824,
        aqw + (size_t)i * 1769472, apw + (size_t)i * 589824,
        f1w + (size_t)i * 2359296, f2w + (size_t)i * 2359296, wbf);

    // ---- time attention (uses norm3) ----
    ln_bf16_kernel<<<M, 256, 0, stream>>>(xt, n3s + i * 768, n3b + i * 768, abf);
    gemm_bt<0><<<dim3(18, 50), 256, 0, stream>>>(abf, wbf + O_TQ, tqb + (size_t)i * 2304,
                                                 nullptr, qkv, nullptr, 2304, 768);
    cls_attn_kernel<<<48, 256, 0, stream>>>(qkv, abf);
    time_attn_kernel<<<2352, 256, 0, stream>>>(qkv, abf);
    gemm_bt<1><<<dim3(6, 50), 256, 0, stream>>>(abf, wbf + O_TP, tpb + (size_t)i * 768,
                                                xt, rs, nullptr, 768, 768);

    // ---- space attention (uses norm1), residual from xt ----
    ln_bf16_kernel<<<M, 256, 0, stream>>>(rs, n1s + i * 768, n1b + i * 768, abf);
    gemm_bt<0><<<dim3(18, 50), 256, 0, stream>>>(abf, wbf + O_AQ, aqb + (size_t)i * 2304,
                                                 nullptr, qkv, nullptr, 2304, 768);
    cls_attn_kernel<<<48, 256, 0, stream>>>(qkv, abf);
    space_attn_kernel<<<384, 256, 0, stream>>>(qkv, abf);
    gemm_bt<1><<<dim3(6, 50), 256, 0, stream>>>(abf, wbf + O_AP, apb + (size_t)i * 768,
                                                xt, rs, nullptr, 768, 768);

    // ---- MLP (uses norm2), residual from space_res (rs) ----
    ln_bf16_kernel<<<M, 256, 0, stream>>>(rs, n2s + i * 768, n2b + i * 768, abf);
    gemm_bt<2><<<dim3(24, 50), 256, 0, stream>>>(abf, wbf + O_F1, f1b + (size_t)i * 3072,
                                                 nullptr, nullptr, hdn, 3072, 768);
    gemm_bt<1><<<dim3(6, 50), 256, 0, stream>>>(hdn, wbf + O_F2, f2b + (size_t)i * 768,
                                                rs, xt, nullptr, 768, 3072);
  }

  ln_final_kernel<<<4, 256, 0, stream>>>(xt, nfs, nfb, outp);
}

// Round 2
// 7435.328 us; speedup vs baseline: 1.2479x; 1.2479x over previous
//
#include <hip/hip_runtime.h>
#include <hip/hip_bf16.h>

// ---------------------------------------------------------------------------
// SpaceTimeTransformer (TimeSformer divided space-time attention) on MI355X.
// Round 2: MFMA space attention (f16 16x16x32), wave-per-row LayerNorm.
// B=4, F=8, N=196, S=1569, D=768, H=12, d=64, L=12, HID=3072.
// ---------------------------------------------------------------------------

#define DEV __device__ __forceinline__

typedef __bf16 bf16x8 __attribute__((ext_vector_type(8)));
typedef float f32x4 __attribute__((ext_vector_type(4)));
typedef _Float16 f16;
typedef _Float16 f16x8 __attribute__((ext_vector_type(8)));
typedef _Float16 f16x4 __attribute__((ext_vector_type(4)));

static constexpr int D = 768;
static constexpr int S = 1569;   // 1 + 8*196
static constexpr int B = 4;
static constexpr int NH = 12;
static constexpr int NF = 8;
static constexpr int NP = 196;
static constexpr int M  = B * S;        // 6276

DEV void gload16(const void* g, void* l) {
  __builtin_amdgcn_global_load_lds((const __attribute__((address_space(1))) void*)g,
                                   (__attribute__((address_space(3))) void*)l, 16, 0, 0);
}

DEV ushort f2bfu(float f) {
  __hip_bfloat16 h = __float2bfloat16(f);
  return *reinterpret_cast<ushort*>(&h);
}

// ---------------------------------------------------------------------------
// Generic GEMM: C[M x N] = A[M x K] @ B[N x K]^T + bias, epilogue variants.
// EPI 0: Cf = acc + bias                (fp32 out)
// EPI 1: Cf = acc + bias + res          (fp32 out)
// EPI 2: Cb = bf16(gelu(acc + bias))    (bf16 out)
// grid = (N/128, Mtiles). A rows must be readable up to Mtiles*128.
// ---------------------------------------------------------------------------
template<int EPI>
__global__ __launch_bounds__(256)
void gemm_bt(const __hip_bfloat16* __restrict__ A,
             const __hip_bfloat16* __restrict__ Bw,
             const float* __restrict__ bias,
             const float* __restrict__ res,
             float* __restrict__ Cf,
             __hip_bfloat16* __restrict__ Cb,
             int N, int K)
{
  __shared__ __hip_bfloat16 As[128 * 64];
  __shared__ __hip_bfloat16 Bs[128 * 64];
  const int tid  = threadIdx.x;
  const int lane = tid & 63;
  const int wave = tid >> 6;
  const int wm = wave >> 1, wn = wave & 1;
  const int bm = blockIdx.y * 128, bn = blockIdx.x * 128;

  const int srow = lane >> 3;          // row within 8-row chunk
  const int scol = (lane & 7) * 8;     // element col within 64

  const int lrow = lane & 15;
  const int lk   = (lane >> 4) * 8;

  f32x4 acc[4][4] = {};

  for (int k0 = 0; k0 < K; k0 += 64) {
    #pragma unroll
    for (int c = 0; c < 4; ++c) {
      const int r = wave * 32 + c * 8;
      gload16(A  + (size_t)(bm + r + srow) * K + k0 + scol, &As[r * 64]);
      gload16(Bw + (size_t)(bn + r + srow) * K + k0 + scol, &Bs[r * 64]);
    }
    __syncthreads();
    #pragma unroll
    for (int kk = 0; kk < 2; ++kk) {
      bf16x8 af[4], bfr[4];
      #pragma unroll
      for (int m = 0; m < 4; ++m)
        af[m] = *reinterpret_cast<const bf16x8*>(&As[(wm*64 + m*16 + lrow)*64 + kk*32 + lk]);
      #pragma unroll
      for (int n = 0; n < 4; ++n)
        bfr[n] = *reinterpret_cast<const bf16x8*>(&Bs[(wn*64 + n*16 + lrow)*64 + kk*32 + lk]);
      #pragma unroll
      for (int m = 0; m < 4; ++m)
        #pragma unroll
        for (int n = 0; n < 4; ++n)
          acc[m][n] = __builtin_amdgcn_mfma_f32_16x16x32_bf16(af[m], bfr[n], acc[m][n], 0, 0, 0);
    }
    __syncthreads();
  }

  const int crow0 = bm + wm*64 + (lane >> 4) * 4;
  const int ccol0 = bn + wn*64 + (lane & 15);
  #pragma unroll
  for (int m = 0; m < 4; ++m) {
    #pragma unroll
    for (int n = 0; n < 4; ++n) {
      #pragma unroll
      for (int i = 0; i < 4; ++i) {
        const int row = crow0 + m*16 + i;
        const int col = ccol0 + n*16;
        const size_t off = (size_t)row * N + col;
        float v = acc[m][n][i] + bias[col];
        if (EPI == 1) {
          Cf[off] = v + res[off];
        } else if (EPI == 2) {
          float g = 0.5f * v * (1.0f + erff(v * 0.70710678118654752f));
          Cb[off] = __float2bfloat16(g);
        } else {
          Cf[off] = v;
        }
      }
    }
  }
}

// ---------------------------------------------------------------------------
// LayerNorm over D=768, fp32 in -> bf16 out. Wave per row, 4 rows per block.
// grid = 6276/4 = 1569.
// ---------------------------------------------------------------------------
__global__ __launch_bounds__(256)
void ln_bf16_kernel(const float* __restrict__ in, const float* __restrict__ sc,
                    const float* __restrict__ bb, __hip_bfloat16* __restrict__ out)
{
  const int tid = threadIdx.x, w = tid >> 6, lane = tid & 63;
  const int row = blockIdx.x * 4 + w;
  const float* x = in + (size_t)row * D;
  const int c0 = lane * 4;
  float4 v0 = *(const float4*)(x + c0);
  float4 v1 = *(const float4*)(x + 256 + c0);
  float4 v2 = *(const float4*)(x + 512 + c0);
  float s = v0.x+v0.y+v0.z+v0.w + v1.x+v1.y+v1.z+v1.w + v2.x+v2.y+v2.z+v2.w;
  #pragma unroll
  for (int o = 32; o; o >>= 1) s += __shfl_xor(s, o);
  const float mean = s * (1.f / 768.f);
  float var = 0.f;
  #define SQ(t) { float d_ = (t) - mean; var += d_*d_; }
  SQ(v0.x) SQ(v0.y) SQ(v0.z) SQ(v0.w)
  SQ(v1.x) SQ(v1.y) SQ(v1.z) SQ(v1.w)
  SQ(v2.x) SQ(v2.y) SQ(v2.z) SQ(v2.w)
  #undef SQ
  #pragma unroll
  for (int o = 32; o; o >>= 1) var += __shfl_xor(var, o);
  const float r = rsqrtf(var * (1.f / 768.f) + 1e-6f);
  __hip_bfloat16* orow = out + (size_t)row * D;
  #pragma unroll
  for (int c = 0; c < 3; ++c) {
    const int col = c * 256 + c0;
    float4 vv = (c == 0) ? v0 : (c == 1) ? v1 : v2;
    float4 sv = *(const float4*)(sc + col);
    float4 bv = *(const float4*)(bb + col);
    union { ushort us[4]; uint2 u; } pk;
    pk.us[0] = f2bfu((vv.x - mean) * r * sv.x + bv.x);
    pk.us[1] = f2bfu((vv.y - mean) * r * sv.y + bv.y);
    pk.us[2] = f2bfu((vv.z - mean) * r * sv.z + bv.z);
    pk.us[3] = f2bfu((vv.w - mean) * r * sv.w + bv.w);
    *(uint2*)(orow + col) = pk.u;
  }
}

// Final LayerNorm of CLS rows only -> fp32 d_out (4 x 768).
__global__ __launch_bounds__(256)
void ln_final_kernel(const float* __restrict__ in, const float* __restrict__ sc,
                     const float* __restrict__ bb, float* __restrict__ out)
{
  __shared__ float red[4];
  const int b = blockIdx.x, tid = threadIdx.x;
  const float* x = in + (size_t)(b * S) * D;
  float x0 = x[tid], x1 = x[tid + 256], x2 = x[tid + 512];
  float s = x0 + x1 + x2;
  for (int o = 32; o; o >>= 1) s += __shfl_down(s, o);
  if ((tid & 63) == 0) red[tid >> 6] = s;
  __syncthreads();
  const float mean = (red[0] + red[1] + red[2] + red[3]) * (1.f / 768.f);
  __syncthreads();
  const float d0 = x0 - mean, d1 = x1 - mean, d2 = x2 - mean;
  float v = d0*d0 + d1*d1 + d2*d2;
  for (int o = 32; o; o >>= 1) v += __shfl_down(v, o);
  if ((tid & 63) == 0) red[tid >> 6] = v;
  __syncthreads();
  const float var = (red[0] + red[1] + red[2] + red[3]) * (1.f / 768.f);
  const float r = rsqrtf(var + 1e-6f);
  float* orow = out + (size_t)b * D;
  orow[tid]       = d0 * r * sc[tid]       + bb[tid];
  orow[tid + 256] = d1 * r * sc[tid + 256] + bb[tid + 256];
  orow[tid + 512] = d2 * r * sc[tid + 512] + bb[tid + 512];
}

// ---------------------------------------------------------------------------
// CLS attention: per (b,h), 1 query over all S=1569 keys. grid = 48.
// ---------------------------------------------------------------------------
__global__ __launch_bounds__(256)
void cls_attn_kernel(const float* __restrict__ qkv, __hip_bfloat16* __restrict__ out)
{
  __shared__ float qs[64];
  __shared__ float sims[S];
  __shared__ float opart[4][64];
  __shared__ float red[4];
  const int b = blockIdx.x / NH, h = blockIdx.x % NH;
  const int tid = threadIdx.x;
  const float* base = qkv + (size_t)b * S * 2304;
  if (tid < 64) qs[tid] = base[h * 64 + tid] * 0.125f;
  __syncthreads();
  float lmax = -1e30f;
  for (int j = tid; j < S; j += 256) {
    const float* kr = base + (size_t)j * 2304 + 768 + h * 64;
    float sacc = 0.f;
    #pragma unroll
    for (int c = 0; c < 16; ++c) {
      float4 kv = *(const float4*)(kr + c * 4);
      sacc += qs[c*4+0]*kv.x + qs[c*4+1]*kv.y + qs[c*4+2]*kv.z + qs[c*4+3]*kv.w;
    }
    sims[j] = sacc;
    lmax = fmaxf(lmax, sacc);
  }
  for (int o = 32; o; o >>= 1) lmax = fmaxf(lmax, __shfl_down(lmax, o));
  if ((tid & 63) == 0) red[tid >> 6] = lmax;
  __syncthreads();
  const float m = fmaxf(fmaxf(red[0], red[1]), fmaxf(red[2], red[3]));
  __syncthreads();
  float lsum = 0.f;
  for (int j = tid; j < S; j += 256) {
    float p = __expf(sims[j] - m);
    sims[j] = p;
    lsum += p;
  }
  for (int o = 32; o; o >>= 1) lsum += __shfl_down(lsum, o);
  if ((tid & 63) == 0) red[tid >> 6] = lsum;
  __syncthreads();
  const float l = red[0] + red[1] + red[2] + red[3];
  const int wave = tid >> 6, lane = tid & 63;
  float oa = 0.f;
  for (int j = wave; j < S; j += 4) {
    const float* vr = base + (size_t)j * 2304 + 1536 + h * 64;
    oa += sims[j] * vr[lane];
  }
  opart[wave][lane] = oa;
  __syncthreads();
  if (tid < 64) {
    float o = (opart[0][tid] + opart[1][tid] + opart[2][tid] + opart[3][tid]) / l;
    out[(size_t)(b * S) * D + h * 64 + tid] = __float2bfloat16(o);
  }
}

// ---------------------------------------------------------------------------
// Time attention: group = (b,h,n); 8 queries (frames) x 9 keys (CLS + 8).
// One wave per group, 4 groups per block. grid = 2352.
// ---------------------------------------------------------------------------
__global__ __launch_bounds__(256)
void time_attn_kernel(const float* __restrict__ qkv, __hip_bfloat16* __restrict__ out)
{
  __shared__ float Ks[4][9][64];
  __shared__ float Vs[4][9][64];
  const int tid = threadIdx.x;
  const int grp = tid >> 6, lane = tid & 63;
  const int g = blockIdx.x * 4 + grp;
  const int n = g % NP;
  const int h = (g / NP) % NH;
  const int b = g / (NP * NH);
  const float* base = qkv + (size_t)b * S * 2304;
  #pragma unroll
  for (int j = 0; j < 9; ++j) {
    const int sj = (j == 0) ? 0 : (1 + (j - 1) * NP + n);
    const float* r = base + (size_t)sj * 2304 + h * 64;
    Ks[grp][j][lane] = r[768 + lane];
    Vs[grp][j][lane] = r[1536 + lane];
  }
  const int qi = lane >> 3, sub = lane & 7;
  const int sq = 1 + qi * NP + n;
  const float* qp = base + (size_t)sq * 2304 + h * 64 + sub * 8;
  float4 q0 = *(const float4*)qp;
  float4 q1 = *(const float4*)(qp + 4);
  float qf[8] = {q0.x, q0.y, q0.z, q0.w, q1.x, q1.y, q1.z, q1.w};
  #pragma unroll
  for (int t = 0; t < 8; ++t) qf[t] *= 0.125f;
  __syncthreads();
  float sim[9];
  #pragma unroll
  for (int j = 0; j < 9; ++j) {
    float p = 0.f;
    #pragma unroll
    for (int t = 0; t < 8; ++t) p += qf[t] * Ks[grp][j][sub * 8 + t];
    p += __shfl_xor(p, 1, 8);
    p += __shfl_xor(p, 2, 8);
    p += __shfl_xor(p, 4, 8);
    sim[j] = p;
  }
  float m = sim[0];
  #pragma unroll
  for (int j = 1; j < 9; ++j) m = fmaxf(m, sim[j]);
  float l = 0.f;
  #pragma unroll
  for (int j = 0; j < 9; ++j) { sim[j] = __expf(sim[j] - m); l += sim[j]; }
  const float inv = 1.f / l;
  float o[8] = {};
  #pragma unroll
  for (int j = 0; j < 9; ++j)
    #pragma unroll
    for (int t = 0; t < 8; ++t) o[t] += sim[j] * Vs[grp][j][sub * 8 + t];
  union { ushort us[8]; uint4 v; } pk;
  #pragma unroll
  for (int t = 0; t < 8; ++t) pk.us[t] = f2bfu(o[t] * inv);
  *(uint4*)(out + (size_t)(b * S + sq) * D + h * 64 + sub * 8) = pk.v;
}

// ---------------------------------------------------------------------------
// Space attention, MFMA version. One block (4 waves) per (b,h,f); grid 384.
// Per wave: q-tiles of 16 rows. Phase 1: S^T = K·Q^T (13 key-tiles), in-lane
// softmax over keys (+2 shfl_xor), P (f16) -> per-wave LDS strip.
// Phase 2: O = P·V via Vt (transposed V in LDS). Keys padded 197->208,
// tail k-frags (keys 208..223) zeroed in registers.
// LDS: K 26624 + Vt 26624 + P 26624 = 79872 B -> 2 blocks/CU.
// ---------------------------------------------------------------------------
DEV f16* kls_addr(f16* basep, int key, int colb) {
  return (f16*)((char*)basep + key * 128 + (colb ^ ((key & 7) << 4)));
}

__global__ __launch_bounds__(256, 2)
void space_attn_kernel(const float* __restrict__ qkv, __hip_bfloat16* __restrict__ out)
{
  __shared__ f16 Kls[208 * 64];     // [key][dim], 128B rows, XOR-swizzled
  __shared__ f16 Vt[64 * 208];      // [dim][key]
  __shared__ f16 Pls[4][16 * 208];  // per-wave [q_local][key]

  const int tid = threadIdx.x;
  const int f = blockIdx.x & 7;
  const int h = (blockIdx.x >> 3) % NH;
  const int b = blockIdx.x / (NH * NF);
  const float* base = qkv + (size_t)b * S * 2304;

  // ---- stage K (f16, swizzled) and V^T (f16) ----
  for (int idx = tid; idx < 208 * 8; idx += 256) {
    const int key = idx >> 3, ch = idx & 7;
    float k8[8] = {}, v8[8] = {};
    if (key < 197) {
      const int row = (key == 0) ? 0 : 1 + f * NP + key - 1;
      const float* kr = base + (size_t)row * 2304 + 768 + h * 64 + ch * 8;
      float4 a = *(const float4*)kr, b2 = *(const float4*)(kr + 4);
      k8[0]=a.x; k8[1]=a.y; k8[2]=a.z; k8[3]=a.w;
      k8[4]=b2.x; k8[5]=b2.y; k8[6]=b2.z; k8[7]=b2.w;
      float4 c1 = *(const float4*)(kr + 768), c2 = *(const float4*)(kr + 772);
      v8[0]=c1.x; v8[1]=c1.y; v8[2]=c1.z; v8[3]=c1.w;
      v8[4]=c2.x; v8[5]=c2.y; v8[6]=c2.z; v8[7]=c2.w;
    }
    f16x8 kp;
    #pragma unroll
    for (int j = 0; j < 8; ++j) kp[j] = (f16)k8[j];
    *(f16x8*)kls_addr(Kls, key, ch * 16) = kp;
    #pragma unroll
    for (int j = 0; j < 8; ++j) Vt[(ch * 8 + j) * 208 + key] = (f16)v8[j];
  }
  __syncthreads();

  const int w = tid >> 6, lane = tid & 63;
  const int l15 = lane & 15, g = lane >> 4;
  f16* Pw = &Pls[w][0];

  for (int Qt = w; Qt < 13; Qt += 4) {
    // ---- load Q fragments (B operand: col=q, k=dim) ----
    const int qidx = Qt * 16 + l15;                    // may exceed 195 (pad)
    const float* qp = base + (size_t)(1 + f * NP + qidx) * 2304 + h * 64 + g * 8;
    f16x8 q0, q1;
    {
      float4 a = *(const float4*)qp, b2 = *(const float4*)(qp + 4);
      float4 c1 = *(const float4*)(qp + 32), c2 = *(const float4*)(qp + 36);
      q0[0]=(f16)(a.x*0.125f); q0[1]=(f16)(a.y*0.125f); q0[2]=(f16)(a.z*0.125f); q0[3]=(f16)(a.w*0.125f);
      q0[4]=(f16)(b2.x*0.125f); q0[5]=(f16)(b2.y*0.125f); q0[6]=(f16)(b2.z*0.125f); q0[7]=(f16)(b2.w*0.125f);
      q1[0]=(f16)(c1.x*0.125f); q1[1]=(f16)(c1.y*0.125f); q1[2]=(f16)(c1.z*0.125f); q1[3]=(f16)(c1.w*0.125f);
      q1[4]=(f16)(c2.x*0.125f); q1[5]=(f16)(c2.y*0.125f); q1[6]=(f16)(c2.z*0.125f); q1[7]=(f16)(c2.w*0.125f);
    }
    // ---- phase 1: S^T[key][q] over 13 key tiles ----
    f32x4 sacc[13] = {};
    #pragma unroll
    for (int kt = 0; kt < 13; ++kt) {
      const int key = kt * 16 + l15;
      f16x8 a0 = *(const f16x8*)kls_addr(Kls, key, g * 16);
      f16x8 a1 = *(const f16x8*)kls_addr(Kls, key, 64 + g * 16);
      sacc[kt] = __builtin_amdgcn_mfma_f32_16x16x32_f16(a0, q0, sacc[kt], 0, 0, 0);
      sacc[kt] = __builtin_amdgcn_mfma_f32_16x16x32_f16(a1, q1, sacc[kt], 0, 0, 0);
    }
    // mask padded keys (>=197) in last tile: rows 192 + g*4 + i
    #pragma unroll
    for (int i = 0; i < 4; ++i)
      if (g * 4 + i >= 5) sacc[12][i] = -1e30f;
    // ---- softmax over keys (per q column = lane&15) ----
    float mx = -1e30f;
    #pragma unroll
    for (int kt = 0; kt < 13; ++kt)
      #pragma unroll
      for (int i = 0; i < 4; ++i) mx = fmaxf(mx, sacc[kt][i]);
    mx = fmaxf(mx, __shfl_xor(mx, 16));
    mx = fmaxf(mx, __shfl_xor(mx, 32));
    float sum = 0.f;
    #pragma unroll
    for (int kt = 0; kt < 13; ++kt) {
      f16x4 pk;
      #pragma unroll
      for (int i = 0; i < 4; ++i) {
        float p = __expf(sacc[kt][i] - mx);
        sum += p;
        pk[i] = (f16)p;
      }
      *(f16x4*)&Pw[l15 * 208 + kt * 16 + g * 4] = pk;
    }
    sum += __shfl_xor(sum, 16);
    sum += __shfl_xor(sum, 32);
    const float linv = 1.f / sum;
    // ---- phase 2: O[q][dim] = P·V ----
    f32x4 oacc[4] = {};
    #pragma unroll
    for (int kt2 = 0; kt2 < 7; ++kt2) {
      const bool tail = (kt2 == 6) && (g >= 2);   // keys >= 208
      f16x8 pa = {};
      if (!tail) pa = *(const f16x8*)&Pw[l15 * 208 + kt2 * 32 + g * 8];
      #pragma unroll
      for (int dt = 0; dt < 4; ++dt) {
        f16x8 vb = {};
        if (!tail) vb = *(const f16x8*)&Vt[(dt * 16 + l15) * 208 + kt2 * 32 + g * 8];
        oacc[dt] = __builtin_amdgcn_mfma_f32_16x16x32_f16(pa, vb, oacc[dt], 0, 0, 0);
      }
    }
    // ---- store (C frag: row q = g*4+i, col dim = dt*16 + l15) ----
    #pragma unroll
    for (int i = 0; i < 4; ++i) {
      const float lv = __shfl(linv, g * 4 + i);
      const int qo = Qt * 16 + g * 4 + i;
      if (qo < NP) {
        __hip_bfloat16* orow = out + (size_t)(b * S + 1 + f * NP + qo) * D + h * 64 + l15;
        #pragma unroll
        for (int dt = 0; dt < 4; ++dt)
          orow[dt * 16] = __float2bfloat16(oacc[dt][i] * lv);
      }
    }
  }
}

// ---------------------------------------------------------------------------
// Patch embedding im2col: x (4,8,3,224,224) -> A (6272, 768) bf16.
// ---------------------------------------------------------------------------
__global__ __launch_bounds__(256)
void im2col_kernel(const float* __restrict__ x, __hip_bfloat16* __restrict__ A)
{
  const int idx = blockIdx.x * 256 + threadIdx.x;   // < 6272*768
  const int col = idx % 768;
  const int row = idx / 768;
  const int px = col & 15, py = (col >> 4) & 15, c = col >> 8;
  const int pw = row % 14, ph = (row / 14) % 14, bf = row / 196;
  const float v = x[(((size_t)bf * 3 + c) * 224 + ph * 16 + py) * 224 + pw * 16 + px];
  A[idx] = __float2bfloat16(v);
}

// Assemble token stream: xt[b][s][d] = patch/cls + pos + temporal embeds.
__global__ __launch_bounds__(256)
void assemble_kernel(const float* __restrict__ xp, const float* __restrict__ cls,
                     const float* __restrict__ pos, const float* __restrict__ temb,
                     float* __restrict__ xt)
{
  const int idx = blockIdx.x * 256 + threadIdx.x;   // < 4*1569*768
  const int d = idx % D;
  const int s = (idx / D) % S;
  const int b = idx / (D * S);
  float v;
  if (s == 0) {
    v = cls[d] + pos[d];
  } else {
    const int j = s - 1, f = j / NP, nn = j % NP;
    v = xp[((size_t)(b * NF + f) * NP + nn) * D + d]
        + pos[(size_t)(1 + nn) * D + d] + temb[(size_t)f * D + d];
  }
  xt[((size_t)b * S + s) * D + d] = v;
}

// Convert one layer's 6 weight matrices fp32 -> bf16 into packed buffer.
__global__ __launch_bounds__(256)
void wconv6_kernel(const float* __restrict__ tq, const float* __restrict__ tp,
                   const float* __restrict__ aq, const float* __restrict__ ap,
                   const float* __restrict__ f1, const float* __restrict__ f2,
                   __hip_bfloat16* __restrict__ dst)
{
  const size_t i = ((size_t)blockIdx.x * 256 + threadIdx.x) * 4;  // < 9437184
  const float* src;
  size_t off = i;
  if      (i < 1769472u) { src = tq; }
  else if (i < 2359296u) { src = tp; off = i - 1769472u; }
  else if (i < 4128768u) { src = aq; off = i - 2359296u; }
  else if (i < 4718592u) { src = ap; off = i - 4128768u; }
  else if (i < 7077888u) { src = f1; off = i - 4718592u; }
  else                   { src = f2; off = i - 7077888u; }
  const float4 v = *(const float4*)(src + off);
  union { ushort us[4]; uint2 u; } pk;
  pk.us[0] = f2bfu(v.x); pk.us[1] = f2bfu(v.y);
  pk.us[2] = f2bfu(v.z); pk.us[3] = f2bfu(v.w);
  *(uint2*)(dst + i) = pk.u;
}

__global__ __launch_bounds__(256)
void wconv1_kernel(const float* __restrict__ src, __hip_bfloat16* __restrict__ dst)
{
  const size_t i = ((size_t)blockIdx.x * 256 + threadIdx.x) * 4;  // < 589824
  const float4 v = *(const float4*)(src + i);
  union { ushort us[4]; uint2 u; } pk;
  pk.us[0] = f2bfu(v.x); pk.us[1] = f2bfu(v.y);
  pk.us[2] = f2bfu(v.z); pk.us[3] = f2bfu(v.w);
  *(uint2*)(dst + i) = pk.u;
}

// ---------------------------------------------------------------------------
extern "C" void kernel_launch(void* const* d_in, const int* in_sizes, int n_in,
                              void* d_out, int out_size, void* d_ws, size_t ws_size,
                              hipStream_t stream) {
  (void)in_sizes; (void)n_in; (void)out_size; (void)ws_size;
  const float* x       = (const float*)d_in[0];
  const float* patch_w = (const float*)d_in[1];
  const float* patch_b = (const float*)d_in[2];
  const float* cls_t   = (const float*)d_in[3];
  const float* pos_e   = (const float*)d_in[4];
  const float* tem_e   = (const float*)d_in[5];
  const float* n1s = (const float*)d_in[6];
  const float* n1b = (const float*)d_in[7];
  const float* n2s = (const float*)d_in[8];
  const float* n2b = (const float*)d_in[9];
  const float* n3s = (const float*)d_in[10];
  const float* n3b = (const float*)d_in[11];
  const float* aqw = (const float*)d_in[12];
  const float* aqb = (const float*)d_in[13];
  const float* apw = (const float*)d_in[14];
  const float* apb = (const float*)d_in[15];
  const float* tqw = (const float*)d_in[16];
  const float* tqb = (const float*)d_in[17];
  const float* tpw = (const float*)d_in[18];
  const float* tpb = (const float*)d_in[19];
  const float* f1w = (const float*)d_in[20];
  const float* f1b = (const float*)d_in[21];
  const float* f2w = (const float*)d_in[22];
  const float* f2b = (const float*)d_in[23];
  const float* nfs = (const float*)d_in[24];
  const float* nfb = (const float*)d_in[25];
  float* outp = (float*)d_out;

  // workspace layout (bytes)
  char* ws = (char*)d_ws;
  float* xt  = (float*)(ws);                          // 6400*768 f32
  float* rs  = (float*)(ws + 19660800);               // 6400*768 f32
  float* qkv = (float*)(ws + 39321600);               // 6400*2304 f32
  __hip_bfloat16* abf = (__hip_bfloat16*)(ws + 98304000);   // 6400*3072 bf16
  __hip_bfloat16* wbf = (__hip_bfloat16*)(ws + 137625600);  // 9,437,184 bf16
  __hip_bfloat16* hdn = (__hip_bfloat16*)qkv;         // fc1 gelu out aliases qkv buf

  // weight segment offsets (elements)
  const size_t O_TQ = 0, O_TP = 1769472, O_AQ = 2359296, O_AP = 4128768,
               O_F1 = 4718592, O_F2 = 7077888;

  // ---- patch embedding ----
  im2col_kernel<<<18816, 256, 0, stream>>>(x, abf);
  wconv1_kernel<<<576, 256, 0, stream>>>(patch_w, wbf);
  gemm_bt<0><<<dim3(6, 49), 256, 0, stream>>>(abf, wbf, patch_b, nullptr, qkv, nullptr, 768, 768);
  assemble_kernel<<<18828, 256, 0, stream>>>(qkv, cls_t, pos_e, tem_e, xt);

  for (int i = 0; i < 12; ++i) {
    wconv6_kernel<<<9216, 256, 0, stream>>>(
        tqw + (size_t)i * 1769472, tpw + (size_t)i * 589824,
        aqw + (size_t)i * 1769472, apw + (size_t)i * 589824,
        f1w + (size_t)i * 2359296, f2w + (size_t)i * 2359296, wbf);

    // ---- time attention (uses norm3) ----
    ln_bf16_kernel<<<1569, 256, 0, stream>>>(xt, n3s + i * 768, n3b + i * 768, abf);
    gemm_bt<0><<<dim3(18, 50), 256, 0, stream>>>(abf, wbf + O_TQ, tqb + (size_t)i * 2304,
                                                 nullptr, qkv, nullptr, 2304, 768);
    cls_attn_kernel<<<48, 256, 0, stream>>>(qkv, abf);
    time_attn_kernel<<<2352, 256, 0, stream>>>(qkv, abf);
    gemm_bt<1><<<dim3(6, 50), 256, 0, stream>>>(abf, wbf + O_TP, tpb + (size_t)i * 768,
                                                xt, rs, nullptr, 768, 768);

    // ---- space attention (uses norm1), residual from xt ----
    ln_bf16_kernel<<<1569, 256, 0, stream>>>(rs, n1s + i * 768, n1b + i * 768, abf);
    gemm_bt<0><<<dim3(18, 50), 256, 0, stream>>>(abf, wbf + O_AQ, aqb + (size_t)i * 2304,
                                                 nullptr, qkv, nullptr, 2304, 768);
    cls_attn_kernel<<<48, 256, 0, stream>>>(qkv, abf);
    space_attn_kernel<<<384, 256, 0, stream>>>(qkv, abf);
    gemm_bt<1><<<dim3(6, 50), 256, 0, stream>>>(abf, wbf + O_AP, apb + (size_t)i * 768,
                                                xt, rs, nullptr, 768, 768);

    // ---- MLP (uses norm2), residual from space_res (rs) ----
    ln_bf16_kernel<<<1569, 256, 0, stream>>>(rs, n2s + i * 768, n2b + i * 768, abf);
    gemm_bt<2><<<dim3(24, 50), 256, 0, stream>>>(abf, wbf + O_F1, f1b + (size_t)i * 3072,
                                                 nullptr, nullptr, hdn, 3072, 768);
    gemm_bt<1><<<dim3(6, 50), 256, 0, stream>>>(hdn, wbf + O_F2, f2b + (size_t)i * 768,
                                                rs, xt, nullptr, 768, 3072);
  }

  ln_final_kernel<<<4, 256, 0, stream>>>(xt, nfs, nfb, outp);
}